// Round 4
// baseline (597.750 us; speedup 1.0000x reference)
//
#include <hip/hip_runtime.h>

// Fused 2-layer LSTM (B=4096, S=512, H=64) + dense(64->32 relu)->dense(32->24).
// R7: 1024 thr / 16 waves (4/SIMD), grid=256, designed to fit the compiler's
// hard 64-VGPR clamp for 1024-thr WGs (R4/R5/R6: attributes+LDS pad all ignored;
// clamp produced 6-reg spill = 22B/thread scratch traffic).
// Wave pairs split the reduction dimension so no wave holds >32 weight VGPRs:
//   L1 pair (ct, kh):  each holds one K-half of Whh1 (16 VGPR), 4 MFMAs, 1 A-read.
//   L2 pair (ct, mh):  mh=0 holds Wih2, mh=1 holds Whh2 (32 VGPR), 8 MFMAs, 2 A-reads.
// Partial z tiles are summed via a padded LDS exchange (pitch-35 slots ~2-way
// banked = free per m136) with a second barrier per step; each wave then runs
// gate math for its 2 row-slots (rows quad*4+2hf+{0,1}) and writes h.
// This also DEDUPLICATES all MFMAs (192->96 issues/CU/step) and halves A-reads.
// Single recurrence barrier structure kept: parity double-buffered h1/h2,
// layer-2 delayed 1 step (z2[t-1] = b2 + Wih2@h1[t-1] + Whh2@h2[t-2]).
// Gate math: 5 exp + 2 rcp per element (i/f/g denominators merged).

typedef __attribute__((ext_vector_type(8))) short bf16x8;
typedef __attribute__((ext_vector_type(4))) float floatx4;

#define SEQ 512
#define HID 64
#define LOG2E 1.4426950408889634f
#define ZXP 35           // floats per row-pair exchange slot (odd-ish pitch -> ~2-way banks)
#define GSTRIDE (8 * ZXP) // per-gate stride in exchange buffer

__device__ inline floatx4 MFMA(bf16x8 a, bf16x8 b, floatx4 c) {
    return __builtin_amdgcn_mfma_f32_16x16x32_bf16(a, b, c, 0, 0, 0);
}
__device__ inline short f2bf(float f) {
    __bf16 b = (__bf16)f;
    return __builtin_bit_cast(short, b);
}
__device__ inline float exp2_fast(float x) {
#if __has_builtin(__builtin_amdgcn_exp2f)
    return __builtin_amdgcn_exp2f(x);
#else
    return __expf(x * 0.6931471805599453f);
#endif
}
__device__ inline float rcp_fast(float x) { return __builtin_amdgcn_rcpf(x); }

// z* pre-scaled: zi=-i*log2e, zf=-f*log2e, zg=-2g*log2e, zo=-o*log2e.
// c' = [c*(1+ei)(1+eg) + (1-eg)(1+ef)] / [(1+ef)(1+ei)(1+eg)]  (merged rcp)
// h  = sigm(o)*tanh(c') = (1-ec)/((1+eo)(1+ec)),  ec = e^{-2c'} (clamped)
__device__ inline float lstm_gate(float zi, float zf, float zg, float zo, float& c) {
    float ei = exp2_fast(zi);
    float ef = exp2_fast(zf);
    float eg = exp2_fast(zg);
    float eo = exp2_fast(zo);
    float P  = (1.0f + ei) * (1.0f + eg);
    float F  = 1.0f + ef;
    float num = c * P + (1.0f - eg) * F;
    c = num * rcp_fast(P * F);
    float ec = exp2_fast(fminf(c * (-2.0f * LOG2E), 40.0f));
    return (1.0f - ec) * rcp_fast((1.0f + eo) * (1.0f + ec));
}

__global__ __launch_bounds__(1024)
void lstm_fused(
    const float* __restrict__ x,
    const float* __restrict__ Wih1, const float* __restrict__ Whh1,
    const float* __restrict__ bih1, const float* __restrict__ bhh1,
    const float* __restrict__ Wih2, const float* __restrict__ Whh2,
    const float* __restrict__ bih2, const float* __restrict__ bhh2,
    const float* __restrict__ Wd1,  const float* __restrict__ bd1,
    const float* __restrict__ Wd2,  const float* __restrict__ bd2,
    float* __restrict__ out)
{
    const int tid  = threadIdx.x;
    const int wid  = tid >> 6;        // 0..15
    const int ct   = wid & 3;         // column-tile (h-cols [16ct,16ct+16))
    const int hf   = (wid >> 2) & 1;  // pair half: kh (L1) / matrix (L2); own rows quad*4+2hf+{0,1}
    const int is2  = wid >> 3;        // waves 0-7: layer-1, 8-15: layer-2
    const int lane = tid & 63;
    const int l15  = lane & 15;
    const int quad = lane >> 4;
    const int b0   = blockIdx.x * 16;

    __shared__ __align__(16) float x_s[16][516];
    __shared__ __align__(16) short h1_s[2][16][72];
    __shared__ __align__(16) short h2_s[2][16][72];
    __shared__ float y1_s[16][32];
    __shared__ float zx1_s[4 * 4 * 8 * ZXP];   // L1 partial-z exchange
    __shared__ float zx2_s[4 * 4 * 8 * ZXP];   // L2 partial-z exchange
    __shared__ float pad_s[600];               // push LDS > 80KB: guarantee 1 WG/CU dispatch
    if (blockIdx.x == 0xFFFFFFFFu) ((volatile float*)pad_s)[tid & 511] = 1.0f;

    // ---- stage x tile (16 rows x 512 f32) ----
    {
        const int row = wid;
        const int c0  = lane * 8;
        const float4* src = reinterpret_cast<const float4*>(x + (size_t)(b0 + row) * SEQ + c0);
        float4* dst = reinterpret_cast<float4*>(&x_s[row][c0]);
        dst[0] = src[0];
        dst[1] = src[1];
    }
    for (int i = tid; i < 2 * 16 * 72; i += 1024) {
        (&h1_s[0][0][0])[i] = 0;
        (&h2_s[0][0][0])[i] = 0;
    }

    const int hcol  = ct * 16 + l15;
    const int rb    = quad * 4 + hf * 2;                              // own first row
    const int zx_wr = ((ct * 4) * 8 + 2 * quad + (1 - hf)) * ZXP + l15 * 2;  // write OTHER half's rows
    const int zx_rd = ((ct * 4) * 8 + 2 * quad + hf) * ZXP + l15 * 2;        // read OWN rows

    if (!is2) {
        // ================= layer-1 waves (ct, kh=hf) =================
        bf16x8 Wf[4];                   // Whh1, one K-half, 4 gates: 16 VGPR
        float wxc[4], bcs[4];
        #pragma unroll
        for (int g = 0; g < 4; ++g) {
            const float sc = (g == 2) ? (-2.0f * LOG2E) : (-LOG2E);
            const int col = g * 64 + hcol;
            wxc[g] = Wih1[col] * sc;
            bcs[g] = hf ? 0.0f : (bih1[col] + bhh1[col]) * sc;   // bias counted once (hf=0)
            const int koff = hf * 32 + quad * 8;
            union { short s[8]; bf16x8 v; } u;
            #pragma unroll
            for (int j = 0; j < 8; ++j)
                u.s[j] = f2bf(Whh1[col * HID + koff + j] * sc);
            Wf[g] = u.v;
        }
        float cst[2] = {0, 0};
        #pragma unroll 2
        for (int t = 0; t < SEQ; ++t) {
            const int pr1 = (t + 1) & 1;   // holds h1[t-1]
            const int pr2 = t & 1;         // receives h1[t]
            __syncthreads();               // barA
            const bf16x8 A = *reinterpret_cast<const bf16x8*>(&h1_s[pr1][l15][hf * 32 + quad * 8]);
            floatx4 z[4];
            #pragma unroll
            for (int g = 0; g < 4; ++g) z[g] = floatx4{bcs[g], bcs[g], bcs[g], bcs[g]};
            #pragma unroll
            for (int g = 0; g < 4; ++g) z[g] = MFMA(A, Wf[g], z[g]);
            if (hf == 0) {                 // write rows {2,3} partials for partner
                #pragma unroll
                for (int g = 0; g < 4; ++g) {
                    zx1_s[zx_wr + g * GSTRIDE]     = z[g][2];
                    zx1_s[zx_wr + g * GSTRIDE + 1] = z[g][3];
                }
            } else {                       // write rows {0,1}
                #pragma unroll
                for (int g = 0; g < 4; ++g) {
                    zx1_s[zx_wr + g * GSTRIDE]     = z[g][0];
                    zx1_s[zx_wr + g * GSTRIDE + 1] = z[g][1];
                }
            }
            __syncthreads();               // barB
            const float xa = x_s[rb][t];
            const float xb = x_s[rb + 1][t];
            if (hf == 0) {
                #pragma unroll
                for (int g = 0; g < 4; ++g) {
                    z[g][0] += zx1_s[zx_rd + g * GSTRIDE]     + xa * wxc[g];
                    z[g][1] += zx1_s[zx_rd + g * GSTRIDE + 1] + xb * wxc[g];
                }
                float h1v = lstm_gate(z[0][0], z[1][0], z[2][0], z[3][0], cst[0]);
                h1_s[pr2][rb][hcol] = f2bf(h1v);
                h1v = lstm_gate(z[0][1], z[1][1], z[2][1], z[3][1], cst[1]);
                h1_s[pr2][rb + 1][hcol] = f2bf(h1v);
            } else {
                #pragma unroll
                for (int g = 0; g < 4; ++g) {
                    z[g][2] += zx1_s[zx_rd + g * GSTRIDE]     + xa * wxc[g];
                    z[g][3] += zx1_s[zx_rd + g * GSTRIDE + 1] + xb * wxc[g];
                }
                float h1v = lstm_gate(z[0][2], z[1][2], z[2][2], z[3][2], cst[0]);
                h1_s[pr2][rb][hcol] = f2bf(h1v);
                h1v = lstm_gate(z[0][3], z[1][3], z[2][3], z[3][3], cst[1]);
                h1_s[pr2][rb + 1][hcol] = f2bf(h1v);
            }
        }
        __syncthreads();                   // matches L2 drain barA
        __syncthreads();                   // matches L2 drain barB
    } else {
        // ================= layer-2 waves (ct, mh=hf) =================
        bf16x8 Wf[2][4];                  // mh=0: Wih2, mh=1: Whh2 (both K-halves): 32 VGPR
        float bcs[4];
        const float* __restrict__ M = hf ? Whh2 : Wih2;
        #pragma unroll
        for (int g = 0; g < 4; ++g) {
            const float sc = (g == 2) ? (-2.0f * LOG2E) : (-LOG2E);
            const int col = g * 64 + hcol;
            bcs[g] = hf ? 0.0f : (bih2[col] + bhh2[col]) * sc;
            #pragma unroll
            for (int kt = 0; kt < 2; ++kt) {
                const int koff = kt * 32 + quad * 8;
                union { short s[8]; bf16x8 v; } u;
                #pragma unroll
                for (int j = 0; j < 8; ++j)
                    u.s[j] = f2bf(M[col * HID + koff + j] * sc);
                Wf[kt][g] = u.v;
            }
        }
        float cst[2] = {0, 0};
        #pragma unroll 2
        for (int t = 0; t < SEQ; ++t) {
            const int pr1 = (t + 1) & 1;   // h1[t-1] buffer; receives h2[t-1]
            const int pr2 = t & 1;         // holds h2[t-2]
            __syncthreads();               // barA
            const short* srcp = hf ? &h2_s[pr2][l15][quad * 8] : &h1_s[pr1][l15][quad * 8];
            const bf16x8 Aa = *reinterpret_cast<const bf16x8*>(srcp);
            const bf16x8 Ab = *reinterpret_cast<const bf16x8*>(srcp + 32);
            floatx4 z[4];
            #pragma unroll
            for (int g = 0; g < 4; ++g) z[g] = floatx4{bcs[g], bcs[g], bcs[g], bcs[g]};
            #pragma unroll
            for (int g = 0; g < 4; ++g) z[g] = MFMA(Aa, Wf[0][g], z[g]);
            #pragma unroll
            for (int g = 0; g < 4; ++g) z[g] = MFMA(Ab, Wf[1][g], z[g]);
            if (hf == 0) {
                #pragma unroll
                for (int g = 0; g < 4; ++g) {
                    zx2_s[zx_wr + g * GSTRIDE]     = z[g][2];
                    zx2_s[zx_wr + g * GSTRIDE + 1] = z[g][3];
                }
            } else {
                #pragma unroll
                for (int g = 0; g < 4; ++g) {
                    zx2_s[zx_wr + g * GSTRIDE]     = z[g][0];
                    zx2_s[zx_wr + g * GSTRIDE + 1] = z[g][1];
                }
            }
            __syncthreads();               // barB
            const float m2 = (t == 0) ? 0.0f : 1.0f;  // discard bogus step at t=0
            if (hf == 0) {
                #pragma unroll
                for (int g = 0; g < 4; ++g) {
                    z[g][0] += zx2_s[zx_rd + g * GSTRIDE];
                    z[g][1] += zx2_s[zx_rd + g * GSTRIDE + 1];
                }
                float cc = cst[0];
                float h2v = lstm_gate(z[0][0], z[1][0], z[2][0], z[3][0], cc) * m2;
                cst[0] = cc * m2;
                h2_s[pr1][rb][hcol] = f2bf(h2v);
                cc = cst[1];
                h2v = lstm_gate(z[0][1], z[1][1], z[2][1], z[3][1], cc) * m2;
                cst[1] = cc * m2;
                h2_s[pr1][rb + 1][hcol] = f2bf(h2v);
            } else {
                #pragma unroll
                for (int g = 0; g < 4; ++g) {
                    z[g][2] += zx2_s[zx_rd + g * GSTRIDE];
                    z[g][3] += zx2_s[zx_rd + g * GSTRIDE + 1];
                }
                float cc = cst[0];
                float h2v = lstm_gate(z[0][2], z[1][2], z[2][2], z[3][2], cc) * m2;
                cst[0] = cc * m2;
                h2_s[pr1][rb][hcol] = f2bf(h2v);
                cc = cst[1];
                h2v = lstm_gate(z[0][3], z[1][3], z[2][3], z[3][3], cc) * m2;
                cst[1] = cc * m2;
                h2_s[pr1][rb + 1][hcol] = f2bf(h2v);
            }
        }
        // ---- drain: virtual t=512 (pr1=1, pr2=0) computes z2[511] -> h2f ----
        __syncthreads();                   // drain barA
        {
            const short* srcp = hf ? &h2_s[0][l15][quad * 8] : &h1_s[1][l15][quad * 8];
            const bf16x8 Aa = *reinterpret_cast<const bf16x8*>(srcp);
            const bf16x8 Ab = *reinterpret_cast<const bf16x8*>(srcp + 32);
            floatx4 z[4];
            #pragma unroll
            for (int g = 0; g < 4; ++g) z[g] = floatx4{bcs[g], bcs[g], bcs[g], bcs[g]};
            #pragma unroll
            for (int g = 0; g < 4; ++g) z[g] = MFMA(Aa, Wf[0][g], z[g]);
            #pragma unroll
            for (int g = 0; g < 4; ++g) z[g] = MFMA(Ab, Wf[1][g], z[g]);
            if (hf == 0) {
                #pragma unroll
                for (int g = 0; g < 4; ++g) {
                    zx2_s[zx_wr + g * GSTRIDE]     = z[g][2];
                    zx2_s[zx_wr + g * GSTRIDE + 1] = z[g][3];
                }
            } else {
                #pragma unroll
                for (int g = 0; g < 4; ++g) {
                    zx2_s[zx_wr + g * GSTRIDE]     = z[g][0];
                    zx2_s[zx_wr + g * GSTRIDE + 1] = z[g][1];
                }
            }
            __syncthreads();               // drain barB
            float* h2f = &x_s[0][0];       // repurpose x stage as [16][64] f32
            if (hf == 0) {
                #pragma unroll
                for (int g = 0; g < 4; ++g) {
                    z[g][0] += zx2_s[zx_rd + g * GSTRIDE];
                    z[g][1] += zx2_s[zx_rd + g * GSTRIDE + 1];
                }
                float cc = cst[0];
                h2f[rb * HID + hcol] = lstm_gate(z[0][0], z[1][0], z[2][0], z[3][0], cc);
                cc = cst[1];
                h2f[(rb + 1) * HID + hcol] = lstm_gate(z[0][1], z[1][1], z[2][1], z[3][1], cc);
            } else {
                #pragma unroll
                for (int g = 0; g < 4; ++g) {
                    z[g][2] += zx2_s[zx_rd + g * GSTRIDE];
                    z[g][3] += zx2_s[zx_rd + g * GSTRIDE + 1];
                }
                float cc = cst[0];
                h2f[rb * HID + hcol] = lstm_gate(z[0][2], z[1][2], z[2][2], z[3][2], cc);
                cc = cst[1];
                h2f[(rb + 1) * HID + hcol] = lstm_gate(z[0][3], z[1][3], z[2][3], z[3][3], cc);
            }
        }
    }
    __syncthreads();

    // ---- epilogue: relu(h2 @ Wd1^T + bd1) @ Wd2^T + bd2 ----
    const float* h2f = &x_s[0][0];
    for (int idx = tid; idx < 16 * 32; idx += 1024) {
        const int b = idx >> 5, o = idx & 31;
        float acc = bd1[o];
        #pragma unroll 8
        for (int k = 0; k < HID; ++k) acc += h2f[b * HID + k] * Wd1[o * HID + k];
        y1_s[b][o] = fmaxf(acc, 0.0f);
    }
    __syncthreads();
    for (int idx = tid; idx < 16 * 24; idx += 1024) {
        const int b = idx / 24, o = idx - b * 24;
        float acc = bd2[o];
        #pragma unroll 8
        for (int k = 0; k < 32; ++k) acc += y1_s[b][k] * Wd2[o * 32 + k];
        out[(size_t)(b0 + b) * 24 + o] = acc;
    }
}

extern "C" void kernel_launch(void* const* d_in, const int* in_sizes, int n_in,
                              void* d_out, int out_size, void* d_ws, size_t ws_size,
                              hipStream_t stream) {
    const float* x    = (const float*)d_in[0];
    const float* Wih1 = (const float*)d_in[1];
    const float* Whh1 = (const float*)d_in[2];
    const float* bih1 = (const float*)d_in[3];
    const float* bhh1 = (const float*)d_in[4];
    const float* Wih2 = (const float*)d_in[5];
    const float* Whh2 = (const float*)d_in[6];
    const float* bih2 = (const float*)d_in[7];
    const float* bhh2 = (const float*)d_in[8];
    const float* Wd1  = (const float*)d_in[9];
    const float* bd1  = (const float*)d_in[10];
    const float* Wd2  = (const float*)d_in[11];
    const float* bd2  = (const float*)d_in[12];
    float* out = (float*)d_out;

    lstm_fused<<<256, 1024, 0, stream>>>(x, Wih1, Whh1, bih1, bhh1,
                                         Wih2, Whh2, bih2, bhh2,
                                         Wd1, bd1, Wd2, bd2, out);
}

// Round 6
// 484.886 us; speedup vs baseline: 1.2328x; 1.2328x over previous
//
#include <hip/hip_runtime.h>

// Fused 2-layer LSTM (B=4096, S=512, H=64) + dense(64->32 relu)->dense(32->24).
// R9 == R8 resubmit (R8 bench died to a container-level infra failure; kernel
// re-audited: barrier counts match on both wave-uniform paths (514/514), no
// OOB, LDS 56.4KB caps residency at exactly 2 WGs/CU with grid=512).
// Design: proven R3 shape (512 thr, 8 waves = (layer, col-tile), 1 barrier/step,
// no cross-wave exchange) but 8 batch rows per WG and grid = 512 = TWO
// INDEPENDENT WGs PER CU.
// R4-R7 post-mortem: single-WG designs are barrier-locked - all waves stall at
// the same program point, so extra waves/SIMD never covered the per-step drain
// (R7: spills fixed, VALUBusy still 49%, dur 598 vs R3's 443). Two WGs have
// separate barrier domains: when WG-A drains (barrier + ds_read latency + exp
// chains), WG-B issues. Same total per-CU VALU work as R3, uncorrelated stalls.
// Row packing: batch row b (0..7) -> MFMA A-row (b>>1)*4+(b&1), i.e. rows
// {0,1,4,5,8,9,12,13}; other A-rows stay zero. The MFMA C-layout
// (col=lane&15, row=quad*4+reg) then puts each lane's 2 valid rows in
// z[g][0..1] - gate math is 2 elements/lane with NO shuffle and no idle quads,
// so 2 WGs x half-gate-work = exactly R3's per-CU transcendental count.
// MFMA count doubles (half the A rows are zero) but the pipe was ~20% busy.
// 512-thr WGs avoid the 1024-thr 64-VGPR allocator clamp (R3: 76 regs honored).
// Recurrence: parity double-buffered h1/h2, layer-2 delayed 1 step
// (z2[t-1] = b2 + Wih2@h1[t-1] + Whh2@h2[t-2]).
// Gate math: 5 exp + 2 rcp per element (i/f/g denominators merged).

typedef __attribute__((ext_vector_type(8))) short bf16x8;
typedef __attribute__((ext_vector_type(4))) float floatx4;

#define SEQ 512
#define HID 64
#define LOG2E 1.4426950408889634f

__device__ inline floatx4 MFMA(bf16x8 a, bf16x8 b, floatx4 c) {
    return __builtin_amdgcn_mfma_f32_16x16x32_bf16(a, b, c, 0, 0, 0);
}
__device__ inline short f2bf(float f) {
    __bf16 b = (__bf16)f;
    return __builtin_bit_cast(short, b);
}
__device__ inline float exp2_fast(float x) {
#if __has_builtin(__builtin_amdgcn_exp2f)
    return __builtin_amdgcn_exp2f(x);
#else
    return __expf(x * 0.6931471805599453f);
#endif
}
__device__ inline float rcp_fast(float x) { return __builtin_amdgcn_rcpf(x); }

// z* pre-scaled: zi=-i*log2e, zf=-f*log2e, zg=-2g*log2e, zo=-o*log2e.
// c' = [c*(1+ei)(1+eg) + (1-eg)(1+ef)] / [(1+ef)(1+ei)(1+eg)]  (merged rcp)
// h  = sigm(o)*tanh(c') = (1-ec)/((1+eo)(1+ec)),  ec = e^{-2c'} (clamped)
__device__ inline float lstm_gate(float zi, float zf, float zg, float zo, float& c) {
    float ei = exp2_fast(zi);
    float ef = exp2_fast(zf);
    float eg = exp2_fast(zg);
    float eo = exp2_fast(zo);
    float P  = (1.0f + ei) * (1.0f + eg);
    float F  = 1.0f + ef;
    float num = c * P + (1.0f - eg) * F;
    c = num * rcp_fast(P * F);
    float ec = exp2_fast(fminf(c * (-2.0f * LOG2E), 40.0f));
    return (1.0f - ec) * rcp_fast((1.0f + eo) * (1.0f + ec));
}

__global__ __launch_bounds__(512, 4)
void lstm_fused(
    const float* __restrict__ x,
    const float* __restrict__ Wih1, const float* __restrict__ Whh1,
    const float* __restrict__ bih1, const float* __restrict__ bhh1,
    const float* __restrict__ Wih2, const float* __restrict__ Whh2,
    const float* __restrict__ bih2, const float* __restrict__ bhh2,
    const float* __restrict__ Wd1,  const float* __restrict__ bd1,
    const float* __restrict__ Wd2,  const float* __restrict__ bd2,
    float* __restrict__ out)
{
    const int tid  = threadIdx.x;
    const int wid  = tid >> 6;        // 0..7
    const int ct   = wid & 3;         // column-tile (h-cols [16ct,16ct+16))
    const int is2  = wid >> 2;        // waves 0-3: layer-1, 4-7: layer-2
    const int lane = tid & 63;
    const int l15  = lane & 15;
    const int quad = lane >> 4;
    const int b0   = blockIdx.x * 8;

    // Per-lane rows: batch rows {2q, 2q+1} stored at A-rows {4q, 4q+1}.
    __shared__ __align__(16) float x_s[8][516];
    __shared__ __align__(16) short h1_s[2][16][72];
    __shared__ __align__(16) short h2_s[2][16][72];
    __shared__ float y1_s[8][32];
    // Pad LDS so 3 WGs don't fit on a CU: 2 WGs/CU is the hard cap and
    // grid=512 = exactly 2 everywhere (even residency, deterministic).
    __shared__ float pad_s[7400];
    if (blockIdx.x == 0xFFFFFFFFu) ((volatile float*)pad_s)[tid] = 1.0f;  // never true; keeps pad_s allocated

    // ---- stage x tile (8 rows x 512 f32): one wave per row ----
    {
        const int row = wid;
        const int c0  = lane * 8;
        const float4* src = reinterpret_cast<const float4*>(x + (size_t)(b0 + row) * SEQ + c0);
        float4* dst = reinterpret_cast<float4*>(&x_s[row][c0]);
        dst[0] = src[0];
        dst[1] = src[1];
    }
    // Zero h buffers: also keeps A-rows {2,3,6,7,10,11,14,15} zero forever.
    for (int i = tid; i < 2 * 16 * 72; i += 512) {
        (&h1_s[0][0][0])[i] = 0;
        (&h2_s[0][0][0])[i] = 0;
    }

    const int hcol = ct * 16 + l15;
    const int ar0  = quad * 4;        // A-row of this lane's first batch row (2q)
    const int xr0  = 2 * quad;        // batch row of z[g][0]

    if (!is2) {
        // ================= layer-1 waves =================
        bf16x8 Wf[2][4];                 // Whh1 K-halves: 32 VGPR
        float wxc[4], bcs[4];
        #pragma unroll
        for (int g = 0; g < 4; ++g) {
            const float sc = (g == 2) ? (-2.0f * LOG2E) : (-LOG2E);
            const int col = g * 64 + hcol;
            wxc[g] = Wih1[col] * sc;
            bcs[g] = (bih1[col] + bhh1[col]) * sc;
            #pragma unroll
            for (int kt = 0; kt < 2; ++kt) {
                const int koff = kt * 32 + quad * 8;
                union { short s[8]; bf16x8 v; } u;
                #pragma unroll
                for (int j = 0; j < 8; ++j)
                    u.s[j] = f2bf(Whh1[col * HID + koff + j] * sc);
                Wf[kt][g] = u.v;
            }
        }
        float cst[2] = {0, 0};
        #pragma unroll 2
        for (int t = 0; t < SEQ; ++t) {
            const int pr1 = (t + 1) & 1;   // holds h1[t-1]
            const int pr2 = t & 1;         // receives h1[t]
            __syncthreads();
            const bf16x8 A1a = *reinterpret_cast<const bf16x8*>(&h1_s[pr1][l15][quad * 8]);
            const bf16x8 A1b = *reinterpret_cast<const bf16x8*>(&h1_s[pr1][l15][32 + quad * 8]);
            const float xa = x_s[xr0][t];
            const float xb = x_s[xr0 + 1][t];
            floatx4 z[4];
            #pragma unroll
            for (int g = 0; g < 4; ++g) {
                z[g] = floatx4{bcs[g], bcs[g], bcs[g], bcs[g]};
                z[g][0] += xa * wxc[g];
                z[g][1] += xb * wxc[g];
            }
            #pragma unroll
            for (int g = 0; g < 4; ++g) z[g] = MFMA(A1a, Wf[0][g], z[g]);
            #pragma unroll
            for (int g = 0; g < 4; ++g) z[g] = MFMA(A1b, Wf[1][g], z[g]);
            // rows 2q, 2q+1 live in z[g][0], z[g][1] (A-row packing)
            float hv = lstm_gate(z[0][0], z[1][0], z[2][0], z[3][0], cst[0]);
            h1_s[pr2][ar0][hcol] = f2bf(hv);
            hv = lstm_gate(z[0][1], z[1][1], z[2][1], z[3][1], cst[1]);
            h1_s[pr2][ar0 + 1][hcol] = f2bf(hv);
        }
        __syncthreads();                  // matches L2 pre-drain barrier
        __syncthreads();                  // matches L2 post-drain barrier
    } else {
        // ================= layer-2 waves =================
        bf16x8 Wf[4][4];                 // Wih2 (0..1) + Whh2 (2..3): 64 VGPR
        float bcs[4];
        #pragma unroll
        for (int g = 0; g < 4; ++g) {
            const float sc = (g == 2) ? (-2.0f * LOG2E) : (-LOG2E);
            const int col = g * 64 + hcol;
            bcs[g] = (bih2[col] + bhh2[col]) * sc;
            #pragma unroll
            for (int kt = 0; kt < 2; ++kt) {
                const int koff = kt * 32 + quad * 8;
                union { short s[8]; bf16x8 v; } u0, u1;
                #pragma unroll
                for (int j = 0; j < 8; ++j) {
                    u0.s[j] = f2bf(Wih2[col * HID + koff + j] * sc);
                    u1.s[j] = f2bf(Whh2[col * HID + koff + j] * sc);
                }
                Wf[kt][g] = u0.v;
                Wf[2 + kt][g] = u1.v;
            }
        }
        float cst[2] = {0, 0};
        #pragma unroll 2
        for (int t = 0; t < SEQ; ++t) {
            const int pr1 = (t + 1) & 1;   // h1[t-1]; receives h2[t-1]
            const int pr2 = t & 1;         // holds h2[t-2]
            __syncthreads();
            const bf16x8 A1a = *reinterpret_cast<const bf16x8*>(&h1_s[pr1][l15][quad * 8]);
            const bf16x8 A1b = *reinterpret_cast<const bf16x8*>(&h1_s[pr1][l15][32 + quad * 8]);
            const bf16x8 A2a = *reinterpret_cast<const bf16x8*>(&h2_s[pr2][l15][quad * 8]);
            const bf16x8 A2b = *reinterpret_cast<const bf16x8*>(&h2_s[pr2][l15][32 + quad * 8]);
            floatx4 z[4];
            #pragma unroll
            for (int g = 0; g < 4; ++g)
                z[g] = floatx4{bcs[g], bcs[g], bcs[g], bcs[g]};
            #pragma unroll
            for (int g = 0; g < 4; ++g) z[g] = MFMA(A1a, Wf[0][g], z[g]);   // Wih2 @ h1[t-1]
            #pragma unroll
            for (int g = 0; g < 4; ++g) z[g] = MFMA(A1b, Wf[1][g], z[g]);
            #pragma unroll
            for (int g = 0; g < 4; ++g) z[g] = MFMA(A2a, Wf[2][g], z[g]);   // Whh2 @ h2[t-2]
            #pragma unroll
            for (int g = 0; g < 4; ++g) z[g] = MFMA(A2b, Wf[3][g], z[g]);
            const float m2 = (t == 0) ? 0.0f : 1.0f;  // discard bogus step at t=0
            float cc = cst[0];
            float hv = lstm_gate(z[0][0], z[1][0], z[2][0], z[3][0], cc) * m2;
            cst[0] = cc * m2;
            h2_s[pr1][ar0][hcol] = f2bf(hv);
            cc = cst[1];
            hv = lstm_gate(z[0][1], z[1][1], z[2][1], z[3][1], cc) * m2;
            cst[1] = cc * m2;
            h2_s[pr1][ar0 + 1][hcol] = f2bf(hv);
        }
        // ---- drain: layer 2 for t = SEQ-1 ----
        __syncthreads();                   // h1[511] now visible
        {
            const bf16x8 A1a = *reinterpret_cast<const bf16x8*>(&h1_s[1][l15][quad * 8]);       // h1[511]
            const bf16x8 A1b = *reinterpret_cast<const bf16x8*>(&h1_s[1][l15][32 + quad * 8]);
            const bf16x8 A2a = *reinterpret_cast<const bf16x8*>(&h2_s[0][l15][quad * 8]);       // h2[510]
            const bf16x8 A2b = *reinterpret_cast<const bf16x8*>(&h2_s[0][l15][32 + quad * 8]);
            floatx4 z[4];
            #pragma unroll
            for (int g = 0; g < 4; ++g) {
                z[g] = floatx4{bcs[g], bcs[g], bcs[g], bcs[g]};
                z[g] = MFMA(A1a, Wf[0][g], z[g]);
                z[g] = MFMA(A1b, Wf[1][g], z[g]);
                z[g] = MFMA(A2a, Wf[2][g], z[g]);
                z[g] = MFMA(A2b, Wf[3][g], z[g]);
            }
            float* h2f = &x_s[0][0];       // repurpose x stage as [8][64] f32
            float cc = cst[0];
            h2f[(size_t)xr0 * HID + hcol] = lstm_gate(z[0][0], z[1][0], z[2][0], z[3][0], cc);
            cc = cst[1];
            h2f[(size_t)(xr0 + 1) * HID + hcol] = lstm_gate(z[0][1], z[1][1], z[2][1], z[3][1], cc);
        }
        __syncthreads();
    }

    // ---- epilogue: relu(h2 @ Wd1^T + bd1) @ Wd2^T + bd2 ----
    const float* h2f = &x_s[0][0];
    for (int idx = tid; idx < 8 * 32; idx += 512) {
        const int b = idx >> 5, o = idx & 31;
        float acc = bd1[o];
        #pragma unroll 8
        for (int k = 0; k < HID; ++k) acc += h2f[b * HID + k] * Wd1[o * HID + k];
        y1_s[b][o] = fmaxf(acc, 0.0f);
    }
    __syncthreads();
    for (int idx = tid; idx < 8 * 24; idx += 512) {
        const int b = idx / 24, o = idx - b * 24;
        float acc = bd2[o];
        #pragma unroll 8
        for (int k = 0; k < 32; ++k) acc += y1_s[b][k] * Wd2[o * 32 + k];
        out[(size_t)(b0 + b) * 24 + o] = acc;
    }
}

extern "C" void kernel_launch(void* const* d_in, const int* in_sizes, int n_in,
                              void* d_out, int out_size, void* d_ws, size_t ws_size,
                              hipStream_t stream) {
    const float* x    = (const float*)d_in[0];
    const float* Wih1 = (const float*)d_in[1];
    const float* Whh1 = (const float*)d_in[2];
    const float* bih1 = (const float*)d_in[3];
    const float* bhh1 = (const float*)d_in[4];
    const float* Wih2 = (const float*)d_in[5];
    const float* Whh2 = (const float*)d_in[6];
    const float* bih2 = (const float*)d_in[7];
    const float* bhh2 = (const float*)d_in[8];
    const float* Wd1  = (const float*)d_in[9];
    const float* bd1  = (const float*)d_in[10];
    const float* Wd2  = (const float*)d_in[11];
    const float* bd2  = (const float*)d_in[12];
    float* out = (float*)d_out;

    lstm_fused<<<512, 512, 0, stream>>>(x, Wih1, Whh1, bih1, bhh1,
                                        Wih2, Whh2, bih2, bhh2,
                                        Wd1, bd1, Wd2, bd2, out);
}